// Round 7
// baseline (162.794 us; speedup 1.0000x reference)
//
#include <hip/hip_runtime.h>
#include <cmath>

#define NN    4096
#define FIN   32
#define KSEL  39      // neighbors kept (top-40 minus self)
#define PP    22
#define PPAD  24
#define FOUT  48
#define WPB   2       // waves per block
#define QW    4       // queries per wave
#define CAP   128     // candidate cap per query (fallback if exceeded)
#define WCOLS 32      // combined weight columns: [Wf(22) | pad(2) | Ws(4) | pad(4)]

#define WSYNC() asm volatile("s_waitcnt lgkmcnt(0)" ::: "memory")

__device__ __forceinline__ int lane_prefix(unsigned long long m) {
    return __builtin_amdgcn_mbcnt_hi((unsigned)(m >> 32),
           __builtin_amdgcn_mbcnt_lo((unsigned)m, 0));
}
// order-preserving float->uint map (total order, handles negatives)
__device__ __forceinline__ unsigned ford(float f) {
    int u = __float_as_int(f);
    return (u >= 0) ? ((unsigned)u | 0x80000000u) : ~(unsigned)u;
}
__device__ __forceinline__ float funord(unsigned k) {
    unsigned v = (k & 0x80000000u) ? (k & 0x7FFFFFFFu) : ~k;
    return __uint_as_float(v);
}
// broadcast lane l's value (l must be wave-uniform; here a literal)
__device__ __forceinline__ float lane_bcast(float v, int l) {
    return __uint_as_float((unsigned)__builtin_amdgcn_readlane((int)__float_as_uint(v), l));
}

// ---------------- precompute: 4 threads per point, LDS-staged weights ------------
__global__ __launch_bounds__(256) void gn_pre(
    const float* __restrict__ x,
    const float* __restrict__ Wf, const float* __restrict__ bf,
    const float* __restrict__ Ws, const float* __restrict__ bs,
    float* __restrict__ coords4, float* __restrict__ feats,
    float* __restrict__ sqn)
{
    __shared__ __align__(16) float sW[FIN * WCOLS];
    __shared__ float sB[WCOLS];

    int t = threadIdx.x;
    for (int idx = t; idx < FIN * WCOLS; idx += 256) {
        int i = idx >> 5, c = idx & 31;
        float v = 0.f;
        if (c < PP) v = Wf[i * PP + c];
        else if (c >= 24 && c < 28) v = Ws[i * 4 + (c - 24)];
        sW[idx] = v;
    }
    if (t < WCOLS) {
        float v = 0.f;
        if (t < PP) v = bf[t];
        else if (t >= 24 && t < 28) v = bs[t - 24];
        sB[t] = v;
    }
    __syncthreads();

    int gid = blockIdx.x * 256 + t;
    int p = gid >> 2;          // point
    int h = gid & 3;           // column strip
    int c0 = h * 8;

    const float4* xr4 = (const float4*)(x + (size_t)p * FIN);
    float acc[8];
    #pragma unroll
    for (int k = 0; k < 8; ++k) acc[k] = sB[c0 + k];

    #pragma unroll
    for (int i = 0; i < 8; ++i) {
        float4 xt = xr4[i];
        const float* w0 = sW + (4 * i + 0) * WCOLS + c0;
        const float* w1 = sW + (4 * i + 1) * WCOLS + c0;
        const float* w2 = sW + (4 * i + 2) * WCOLS + c0;
        const float* w3 = sW + (4 * i + 3) * WCOLS + c0;
        #pragma unroll
        for (int k = 0; k < 8; ++k) acc[k] = fmaf(xt.x, w0[k], acc[k]);
        #pragma unroll
        for (int k = 0; k < 8; ++k) acc[k] = fmaf(xt.y, w1[k], acc[k]);
        #pragma unroll
        for (int k = 0; k < 8; ++k) acc[k] = fmaf(xt.z, w2[k], acc[k]);
        #pragma unroll
        for (int k = 0; k < 8; ++k) acc[k] = fmaf(xt.w, w3[k], acc[k]);
    }

    if (h < 3) {
        float4* fw = (float4*)(feats + (size_t)p * PPAD + c0);
        fw[0] = make_float4(acc[0], acc[1], acc[2], acc[3]);
        fw[1] = make_float4(acc[4], acc[5], acc[6], acc[7]);   // h=2: cols 22,23 exact 0
    } else {
        ((float4*)coords4)[p] = make_float4(acc[0], acc[1], acc[2], acc[3]);
        sqn[p] = fmaf(acc[0], acc[0], fmaf(acc[1], acc[1],
                 fmaf(acc[2], acc[2], acc[3] * acc[3])));
    }
}

// ---- fallback-only helpers (degenerate C > CAP path) ----------------------------
__device__ __forceinline__ void sort64_pair(float& v, int& m, int lane) {
    #pragma unroll
    for (int k = 2; k <= 64; k <<= 1) {
        #pragma unroll
        for (int j = k >> 1; j >= 1; j >>= 1) {
            float ov = __shfl_xor(v, j);
            int   om = __shfl_xor(m, j);
            bool keepMin = (((lane & j) == 0) == ((lane & k) == 0));
            bool less = (ov < v) || (ov == v && om < m);
            bool take = (less == keepMin);
            v = take ? ov : v;
            m = take ? om : m;
        }
    }
}
__device__ __forceinline__ void merge64(float& Lv, int& Lm, float cv, int cm, int lane) {
    float rv = __shfl_xor(cv, 63);
    int   rm = __shfl_xor(cm, 63);
    bool less = (rv < Lv) || (rv == Lv && rm < Lm);
    if (less) { Lv = rv; Lm = rm; }
    #pragma unroll
    for (int j = 32; j >= 1; j >>= 1) {
        float ov = __shfl_xor(Lv, j);
        int   om = __shfl_xor(Lm, j);
        bool lower = ((lane & j) == 0);
        bool l2 = (ov < Lv) || (ov == Lv && om < Lm);
        bool take = (l2 == lower);
        Lv = take ? ov : Lv;
        Lm = take ? om : Lm;
    }
}

// ------- per-query selection + staging + packed aggregate (NO epilogue here) -----
// Selection math bit-identical to the verified kernel (sqn values are the exact
// same bits as the in-pass recompute). Returns packed agg:
// lane c<22 -> max_c ; lane 22+c -> mean_c ; others 0.
__device__ __forceinline__ float tail_select(
    int lane, int b, int nj, int C,
    const unsigned short* __restrict__ selq,
    const float4* __restrict__ c4, const float* __restrict__ sqb,
    const float* __restrict__ feats,
    float* __restrict__ fstage)
{
    const float INF = __builtin_inff();
    float4 cqj = c4[nj];
    float sqnj = sqb[nj];

    if (C <= CAP) {
        unsigned kd0 = 0xFFFFFFFFu, ki0 = 0xFFFFFFFFu; float dv0 = 0.f;
        if (lane < C) {
            unsigned idx = (unsigned)selq[lane];
            float4 cm = c4[idx];
            float s2 = sqb[idx];
            float dt = fmaf(cqj.x, cm.x, fmaf(cqj.y, cm.y, fmaf(cqj.z, cm.z, cqj.w * cm.w)));
            float d  = fmaxf(fmaf(-2.f, dt, s2 + sqnj), 0.f);
            dv0 = d; kd0 = __float_as_uint(d); ki0 = idx;
        }
        unsigned kd1 = 0xFFFFFFFFu, ki1 = 0xFFFFFFFFu; float dv1 = 0.f;
        if (64 + lane < C) {
            unsigned idx = (unsigned)selq[64 + lane];
            float4 cm = c4[idx];
            float s2 = sqb[idx];
            float dt = fmaf(cqj.x, cm.x, fmaf(cqj.y, cm.y, fmaf(cqj.z, cm.z, cqj.w * cm.w)));
            float d  = fmaxf(fmaf(-2.f, dt, s2 + sqnj), 0.f);
            dv1 = d; kd1 = __float_as_uint(d); ki1 = idx;
        }
        // D = exact 39th-smallest clamped d2 bits (must stay exact)
        unsigned D = 0;
        for (int bit = 30; bit >= 0; --bit) {
            unsigned t = D | (1u << bit);
            int c = (int)__popcll(__ballot(kd0 < t))
                  + (int)__popcll(__ballot(kd1 < t));
            if (c < KSEL) D = t;
        }
        int cless  = (int)__popcll(__ballot(kd0 < D))
                   + (int)__popcll(__ballot(kd1 < D));
        int tiecnt = (int)__popcll(__ballot(kd0 == D))
                   + (int)__popcll(__ballot(kd1 == D));
        int tneed = KSEL - cless;
        unsigned TI = 0xFFFFFFFFu;
        if (tiecnt > tneed) {            // rare: resolve ties by lowest index
            unsigned pi = 0;
            for (int bit = 11; bit >= 0; --bit) {
                unsigned t = pi | (1u << bit);
                int c = (int)__popcll(__ballot((kd0 == D) && (ki0 < t)))
                      + (int)__popcll(__ballot((kd1 == D) && (ki1 < t)));
                if (c < tneed) pi = t;
            }
            TI = pi;
        }
        // stage the exactly-39 selected neighbors (ballot/prefix slots, no atomics)
        bool take0 = (kd0 < D) || ((kd0 == D) && (ki0 <= TI));
        bool take1 = (kd1 < D) || ((kd1 == D) && (ki1 <= TI));
        unsigned long long tb0 = __ballot(take0);
        unsigned long long tb1 = __ballot(take1);
        unsigned base1 = (unsigned)__popcll(tb0);
        if (take0) {
            unsigned slot = (unsigned)lane_prefix(tb0);
            float wgt = __expf(-10.f * dv0);
            const float4* fr = (const float4*)(feats + ((size_t)b * NN + ki0) * PPAD);
            float4 f0 = fr[0], f1 = fr[1], f2 = fr[2], f3 = fr[3], f4 = fr[4], f5 = fr[5];
            float4* row = (float4*)(fstage + slot * PPAD);
            row[0] = make_float4(f0.x * wgt, f0.y * wgt, f0.z * wgt, f0.w * wgt);
            row[1] = make_float4(f1.x * wgt, f1.y * wgt, f1.z * wgt, f1.w * wgt);
            row[2] = make_float4(f2.x * wgt, f2.y * wgt, f2.z * wgt, f2.w * wgt);
            row[3] = make_float4(f3.x * wgt, f3.y * wgt, f3.z * wgt, f3.w * wgt);
            row[4] = make_float4(f4.x * wgt, f4.y * wgt, f4.z * wgt, f4.w * wgt);
            row[5] = make_float4(f5.x * wgt, f5.y * wgt, f5.z * wgt, f5.w * wgt);
        }
        if (take1) {
            unsigned slot = base1 + (unsigned)lane_prefix(tb1);
            float wgt = __expf(-10.f * dv1);
            const float4* fr = (const float4*)(feats + ((size_t)b * NN + ki1) * PPAD);
            float4 f0 = fr[0], f1 = fr[1], f2 = fr[2], f3 = fr[3], f4 = fr[4], f5 = fr[5];
            float4* row = (float4*)(fstage + slot * PPAD);
            row[0] = make_float4(f0.x * wgt, f0.y * wgt, f0.z * wgt, f0.w * wgt);
            row[1] = make_float4(f1.x * wgt, f1.y * wgt, f1.z * wgt, f1.w * wgt);
            row[2] = make_float4(f2.x * wgt, f2.y * wgt, f2.z * wgt, f2.w * wgt);
            row[3] = make_float4(f3.x * wgt, f3.y * wgt, f3.z * wgt, f3.w * wgt);
            row[4] = make_float4(f4.x * wgt, f4.y * wgt, f4.z * wgt, f4.w * wgt);
            row[5] = make_float4(f5.x * wgt, f5.y * wgt, f5.z * wgt, f5.w * wgt);
        }
    } else {
        // degenerate fallback: exact streaming top-64 over all 4096
        float Lv = INF; int Lm = 0x7FFFFFFF;
        for (int c = 0; c < 64; ++c) {
            int m = c * 64 + lane;
            float4 cm = c4[m];
            float s2 = sqb[m];
            float dt = fmaf(cqj.x, cm.x, fmaf(cqj.y, cm.y, fmaf(cqj.z, cm.z, cqj.w * cm.w)));
            float v  = fmaxf(fmaf(-2.f, dt, s2 + sqnj), 0.f);
            if (m == nj) v = INF;
            sort64_pair(v, m, lane);
            if (c == 0) { Lv = v; Lm = m; }
            else        merge64(Lv, Lm, v, m, lane);
        }
        if (lane < KSEL) {
            float wgt = __expf(-10.f * Lv);
            const float4* fr = (const float4*)(feats + ((size_t)b * NN + Lm) * PPAD);
            float4 f0 = fr[0], f1 = fr[1], f2 = fr[2], f3 = fr[3], f4 = fr[4], f5 = fr[5];
            float4* row = (float4*)(fstage + lane * PPAD);
            row[0] = make_float4(f0.x * wgt, f0.y * wgt, f0.z * wgt, f0.w * wgt);
            row[1] = make_float4(f1.x * wgt, f1.y * wgt, f1.z * wgt, f1.w * wgt);
            row[2] = make_float4(f2.x * wgt, f2.y * wgt, f2.z * wgt, f2.w * wgt);
            row[3] = make_float4(f3.x * wgt, f3.y * wgt, f3.z * wgt, f3.w * wgt);
            row[4] = make_float4(f4.x * wgt, f4.y * wgt, f4.z * wgt, f4.w * wgt);
            row[5] = make_float4(f5.x * wgt, f5.y * wgt, f5.z * wgt, f5.w * wgt);
        }
    }
    WSYNC();

    // ---- packed aggregate over 39 neighbors: 44 lanes, split-k (2x) ----
    // lanes 0..21  : col c, k in [0,20)   -> partial (mx1, sm1)
    // lanes 22..43 : col c, k in [20,39)  -> partial (mx2, sm2)
    // combine via shfl; lane<22 keeps max, lane 22..43 keeps mean.
    float aggv = 0.f;
    if (lane < 2 * PP) {
        bool hi = (lane >= PP);
        int c  = hi ? lane - PP : lane;
        int k0 = hi ? 20 : 0;
        int k1 = hi ? KSEL : 20;
        float mx = -INF, sm = 0.f;
        for (int k = k0; k < k1; ++k) {
            float v = fstage[k * PPAD + c];
            mx = fmaxf(mx, v);
            sm += v;
        }
        int partner = hi ? lane - PP : lane + PP;
        float mxo = __shfl(mx, partner);
        float smo = __shfl(sm, partner);
        aggv = hi ? (smo + sm) * (1.f / (float)KSEL)   // sm1 + sm2
                  : fmaxf(mx, mxo);
    }
    WSYNC();
    return aggv;
}

// ---------------- main: one wave per FOUR queries, fused epilogue ----------------
__global__ __launch_bounds__(WPB * 64, 8) void gn_main(
    const float* __restrict__ x,
    const float* __restrict__ Wo, const float* __restrict__ bo,
    const float* __restrict__ coords4, const float* __restrict__ sqn,
    const float* __restrict__ feats,
    float* __restrict__ out)
{
    __shared__ unsigned short sel_s[WPB * QW * CAP];     // candidate indices
    __shared__ float fstage_s[WPB * KSEL * PPAD];

    const float INF = __builtin_inff();
    const int wv    = threadIdx.x >> 6;
    const int lane  = threadIdx.x & 63;
    const int qbase = (blockIdx.x * WPB + wv) * QW;      // 4 queries, same batch
    const int b     = qbase >> 12;
    const int n0    = qbase & (NN - 1);
    unsigned short* selp = sel_s + wv * QW * CAP;
    float* fstage = fstage_s + wv * (KSEL * PPAD);

    const float4* c4  = ((const float4*)coords4) + (size_t)b * NN;
    const float*  sqb = sqn + (size_t)b * NN;

    // hoisted -2*q components (query coords NOT kept live -- tails reload them).
    // e = s2 - 2*dot, pure 4-FMA chain with s2 loaded (bit-identical values).
    // Selection in e-domain; widened bound keeps an exact superset; tails
    // re-rank with the exact original formula, so final output is unchanged.
    float4 cq0 = c4[n0 + 0], cq1 = c4[n0 + 1], cq2 = c4[n0 + 2], cq3 = c4[n0 + 3];
    float m2x0 = -2.f * cq0.x, m2y0 = -2.f * cq0.y, m2z0 = -2.f * cq0.z, m2w0 = -2.f * cq0.w;
    float m2x1 = -2.f * cq1.x, m2y1 = -2.f * cq1.y, m2z1 = -2.f * cq1.z, m2w1 = -2.f * cq1.w;
    float m2x2 = -2.f * cq2.x, m2y2 = -2.f * cq2.y, m2z2 = -2.f * cq2.z, m2w2 = -2.f * cq2.w;
    float m2x3 = -2.f * cq3.x, m2y3 = -2.f * cq3.y, m2z3 = -2.f * cq3.z, m2w3 = -2.f * cq3.w;

    // ---- pass 1: per-query running min of e (self included) ----
    float km0 = INF, km1 = INF, km2 = INF, km3 = INF;
    #pragma unroll 4
    for (int i = 0; i < 64; ++i) {
        float4 cm = c4[i * 64 + lane];
        float s2  = sqb[i * 64 + lane];
        float e0 = fmaf(m2x0, cm.x, fmaf(m2y0, cm.y, fmaf(m2z0, cm.z, fmaf(m2w0, cm.w, s2))));
        float e1 = fmaf(m2x1, cm.x, fmaf(m2y1, cm.y, fmaf(m2z1, cm.z, fmaf(m2w1, cm.w, s2))));
        float e2 = fmaf(m2x2, cm.x, fmaf(m2y2, cm.y, fmaf(m2z2, cm.z, fmaf(m2w2, cm.w, s2))));
        float e3 = fmaf(m2x3, cm.x, fmaf(m2y3, cm.y, fmaf(m2z3, cm.z, fmaf(m2w3, cm.w, s2))));
        km0 = fminf(km0, e0);
        km1 = fminf(km1, e1);
        km2 = fminf(km2, e2);
        km3 = fminf(km3, e3);
    }
    unsigned kb0 = ford(km0), kb1 = ford(km1), kb2 = ford(km2), kb3 = ford(km3);

    // ---- bound: 40th-smallest lane-min key, TRUNCATED radix (bits 31..15),
    //      widen low 15 bits -> guaranteed >= exact 40th e. Exact superset.
    unsigned ub0 = 0, ub1 = 0, ub2 = 0, ub3 = 0;
    for (int bit = 31; bit >= 15; --bit) {
        unsigned msk = 1u << bit;
        unsigned t0 = ub0 | msk, t1 = ub1 | msk, t2 = ub2 | msk, t3 = ub3 | msk;
        if ((int)__popcll(__ballot(kb0 < t0)) < KSEL + 1) ub0 = t0;
        if ((int)__popcll(__ballot(kb1 < t1)) < KSEL + 1) ub1 = t1;
        if ((int)__popcll(__ballot(kb2 < t2)) < KSEL + 1) ub2 = t2;
        if ((int)__popcll(__ballot(kb3 < t3)) < KSEL + 1) ub3 = t3;
    }
    float UBe0 = funord(ub0 | 0x7FFFu);
    float UBe1 = funord(ub1 | 0x7FFFu);
    float UBe2 = funord(ub2 | 0x7FFFu);
    float UBe3 = funord(ub3 | 0x7FFFu);

    // selves all sit in iteration iSelf at lanes l0..l0+3 (n0 % 4 == 0)
    const int iSelf = n0 >> 6;
    const int l0    = n0 & 63;

    // ---- compact pass: ballot/prefix slot assignment (no LDS atomics) ----
    unsigned cc0 = 0, cc1 = 0, cc2 = 0, cc3 = 0;
    #pragma unroll 4
    for (int i = 0; i < 64; ++i) {
        int m = i * 64 + lane;
        float4 cm = c4[m];
        float s2  = sqb[m];
        float e0 = fmaf(m2x0, cm.x, fmaf(m2y0, cm.y, fmaf(m2z0, cm.z, fmaf(m2w0, cm.w, s2))));
        float e1 = fmaf(m2x1, cm.x, fmaf(m2y1, cm.y, fmaf(m2z1, cm.z, fmaf(m2w1, cm.w, s2))));
        float e2 = fmaf(m2x2, cm.x, fmaf(m2y2, cm.y, fmaf(m2z2, cm.z, fmaf(m2w2, cm.w, s2))));
        float e3 = fmaf(m2x3, cm.x, fmaf(m2y3, cm.y, fmaf(m2z3, cm.z, fmaf(m2w3, cm.w, s2))));
        bool t0 = (e0 <= UBe0);
        bool t1 = (e1 <= UBe1);
        bool t2 = (e2 <= UBe2);
        bool t3 = (e3 <= UBe3);
        if (i == iSelf) {                      // wave-uniform, 1 of 64 iters
            t0 = t0 && (lane != l0 + 0);
            t1 = t1 && (lane != l0 + 1);
            t2 = t2 && (lane != l0 + 2);
            t3 = t3 && (lane != l0 + 3);
        }
        unsigned long long b0 = __ballot(t0);
        unsigned long long b1 = __ballot(t1);
        unsigned long long b2 = __ballot(t2);
        unsigned long long b3 = __ballot(t3);
        if (t0) {
            unsigned s = (cc0 + (unsigned)lane_prefix(b0)) & (CAP - 1);
            selp[0 * CAP + s] = (unsigned short)m;
        }
        if (t1) {
            unsigned s = (cc1 + (unsigned)lane_prefix(b1)) & (CAP - 1);
            selp[1 * CAP + s] = (unsigned short)m;
        }
        if (t2) {
            unsigned s = (cc2 + (unsigned)lane_prefix(b2)) & (CAP - 1);
            selp[2 * CAP + s] = (unsigned short)m;
        }
        if (t3) {
            unsigned s = (cc3 + (unsigned)lane_prefix(b3)) & (CAP - 1);
            selp[3 * CAP + s] = (unsigned short)m;
        }
        cc0 += (unsigned)__popcll(b0);
        cc1 += (unsigned)__popcll(b1);
        cc2 += (unsigned)__popcll(b2);
        cc3 += (unsigned)__popcll(b3);
    }
    WSYNC();

    // ---- four selection/aggregate tails (packed agg kept in VGPRs) ----
    float agg0 = tail_select(lane, b, n0 + 0, (int)cc0, selp + 0 * CAP, c4, sqb, feats, fstage);
    float agg1 = tail_select(lane, b, n0 + 1, (int)cc1, selp + 1 * CAP, c4, sqb, feats, fstage);
    float agg2 = tail_select(lane, b, n0 + 2, (int)cc2, selp + 2 * CAP, c4, sqb, feats, fstage);
    float agg3 = tail_select(lane, b, n0 + 3, (int)cc3, selp + 3 * CAP, c4, sqb, feats, fstage);

    // ---- FUSED epilogue: Wo loaded ONCE for all 4 queries; x via scalar loads ----
    const int qbU = __builtin_amdgcn_readfirstlane(qbase);
    const float* xu = x + (size_t)qbU * FIN;             // uniform -> SMEM loads
    if (lane < FOUT) {
        const float* woL = Wo + lane;
        float bb = bo[lane];
        float a00 = bb, a01 = 0.f, a02 = 0.f, a03 = 0.f;
        float a10 = bb, a11 = 0.f, a12 = 0.f, a13 = 0.f;
        float a20 = bb, a21 = 0.f, a22 = 0.f, a23 = 0.f;
        float a30 = bb, a31 = 0.f, a32 = 0.f, a33 = 0.f;
        #pragma unroll
        for (int f = 0; f < FIN; f += 4) {
            float w0 = woL[(f + 0) * FOUT];
            float w1 = woL[(f + 1) * FOUT];
            float w2 = woL[(f + 2) * FOUT];
            float w3 = woL[(f + 3) * FOUT];
            a00 = fmaf(xu[0 * FIN + f + 0], w0, a00);
            a01 = fmaf(xu[0 * FIN + f + 1], w1, a01);
            a02 = fmaf(xu[0 * FIN + f + 2], w2, a02);
            a03 = fmaf(xu[0 * FIN + f + 3], w3, a03);
            a10 = fmaf(xu[1 * FIN + f + 0], w0, a10);
            a11 = fmaf(xu[1 * FIN + f + 1], w1, a11);
            a12 = fmaf(xu[1 * FIN + f + 2], w2, a12);
            a13 = fmaf(xu[1 * FIN + f + 3], w3, a13);
            a20 = fmaf(xu[2 * FIN + f + 0], w0, a20);
            a21 = fmaf(xu[2 * FIN + f + 1], w1, a21);
            a22 = fmaf(xu[2 * FIN + f + 2], w2, a22);
            a23 = fmaf(xu[2 * FIN + f + 3], w3, a23);
            a30 = fmaf(xu[3 * FIN + f + 0], w0, a30);
            a31 = fmaf(xu[3 * FIN + f + 1], w1, a31);
            a32 = fmaf(xu[3 * FIN + f + 2], w2, a32);
            a33 = fmaf(xu[3 * FIN + f + 3], w3, a33);
        }
        #pragma unroll
        for (int g = 0; g < 2 * PP; g += 4) {
            float w0 = woL[(FIN + g + 0) * FOUT];
            float w1 = woL[(FIN + g + 1) * FOUT];
            float w2 = woL[(FIN + g + 2) * FOUT];
            float w3 = woL[(FIN + g + 3) * FOUT];
            a00 = fmaf(lane_bcast(agg0, g + 0), w0, a00);
            a01 = fmaf(lane_bcast(agg0, g + 1), w1, a01);
            a02 = fmaf(lane_bcast(agg0, g + 2), w2, a02);
            a03 = fmaf(lane_bcast(agg0, g + 3), w3, a03);
            a10 = fmaf(lane_bcast(agg1, g + 0), w0, a10);
            a11 = fmaf(lane_bcast(agg1, g + 1), w1, a11);
            a12 = fmaf(lane_bcast(agg1, g + 2), w2, a12);
            a13 = fmaf(lane_bcast(agg1, g + 3), w3, a13);
            a20 = fmaf(lane_bcast(agg2, g + 0), w0, a20);
            a21 = fmaf(lane_bcast(agg2, g + 1), w1, a21);
            a22 = fmaf(lane_bcast(agg2, g + 2), w2, a22);
            a23 = fmaf(lane_bcast(agg2, g + 3), w3, a23);
            a30 = fmaf(lane_bcast(agg3, g + 0), w0, a30);
            a31 = fmaf(lane_bcast(agg3, g + 1), w1, a31);
            a32 = fmaf(lane_bcast(agg3, g + 2), w2, a32);
            a33 = fmaf(lane_bcast(agg3, g + 3), w3, a33);
        }
        float ac0 = (a00 + a01) + (a02 + a03);
        float ac1 = (a10 + a11) + (a12 + a13);
        float ac2 = (a20 + a21) + (a22 + a23);
        float ac3 = (a30 + a31) + (a32 + a33);
        float e0 = __expf(2.f * ac0);
        float e1 = __expf(2.f * ac1);
        float e2 = __expf(2.f * ac2);
        float e3 = __expf(2.f * ac3);
        float r0 = __builtin_amdgcn_rcpf(e0 + 1.f);
        float r1 = __builtin_amdgcn_rcpf(e1 + 1.f);
        float r2 = __builtin_amdgcn_rcpf(e2 + 1.f);
        float r3 = __builtin_amdgcn_rcpf(e3 + 1.f);
        out[(size_t)(qbU + 0) * FOUT + lane] = fmaf(-2.f, r0, 1.f);
        out[(size_t)(qbU + 1) * FOUT + lane] = fmaf(-2.f, r1, 1.f);
        out[(size_t)(qbU + 2) * FOUT + lane] = fmaf(-2.f, r2, 1.f);
        out[(size_t)(qbU + 3) * FOUT + lane] = fmaf(-2.f, r3, 1.f);
    }
}

extern "C" void kernel_launch(void* const* d_in, const int* in_sizes, int n_in,
                              void* d_out, int out_size, void* d_ws, size_t ws_size,
                              hipStream_t stream) {
    const float* x  = (const float*)d_in[0];
    const float* Wf = (const float*)d_in[1];
    const float* bf = (const float*)d_in[2];
    const float* Ws = (const float*)d_in[3];
    const float* bs = (const float*)d_in[4];
    const float* Wo = (const float*)d_in[5];
    const float* bo = (const float*)d_in[6];
    float* outp = (float*)d_out;

    float* ws      = (float*)d_ws;
    float* coords4 = ws;                      // 32768*4  = 131072 floats
    float* feats   = ws + 131072;             // 32768*24 = 786432 floats
    float* sqn     = ws + 131072 + 786432;    // 32768 floats

    gn_pre<<<(32768 * 4) / 256, 256, 0, stream>>>(x, Wf, bf, Ws, bs, coords4, feats, sqn);
    gn_main<<<32768 / (WPB * QW), WPB * 64, 0, stream>>>(x, Wo, bo, coords4, sqn, feats, outp);
}

// Round 8
// 149.339 us; speedup vs baseline: 1.0901x; 1.0901x over previous
//
#include <hip/hip_runtime.h>
#include <cmath>

#define NN    4096
#define FIN   32
#define KSEL  39      // neighbors kept (top-40 minus self)
#define PP    22
#define PPAD  24
#define FOUT  48
#define WPB   2       // waves per block
#define QW    4       // queries per wave
#define CAP   128     // candidate cap per query (fallback if exceeded)
#define WCOLS 32      // combined weight columns: [Wf(22) | pad(2) | Ws(4) | pad(4)]

#define WSYNC() asm volatile("s_waitcnt lgkmcnt(0)" ::: "memory")

__device__ __forceinline__ int lane_prefix(unsigned long long m) {
    return __builtin_amdgcn_mbcnt_hi((unsigned)(m >> 32),
           __builtin_amdgcn_mbcnt_lo((unsigned)m, 0));
}
// order-preserving float->uint map (total order, handles negatives)
__device__ __forceinline__ unsigned ford(float f) {
    int u = __float_as_int(f);
    return (u >= 0) ? ((unsigned)u | 0x80000000u) : ~(unsigned)u;
}
__device__ __forceinline__ float funord(unsigned k) {
    unsigned v = (k & 0x80000000u) ? (k & 0x7FFFFFFFu) : ~k;
    return __uint_as_float(v);
}
// broadcast lane l's value (l must be wave-uniform; here a literal)
__device__ __forceinline__ float lane_bcast(float v, int l) {
    return __uint_as_float((unsigned)__builtin_amdgcn_readlane((int)__float_as_uint(v), l));
}
// |c|^2 with the EXACT gn_pre FMA order (bit-identical everywhere)
__device__ __forceinline__ float sq4(float4 c) {
    return fmaf(c.x, c.x, fmaf(c.y, c.y, fmaf(c.z, c.z, c.w * c.w)));
}

// ---------------- precompute: 4 threads per point, LDS-staged weights ------------
__global__ __launch_bounds__(256) void gn_pre(
    const float* __restrict__ x,
    const float* __restrict__ Wf, const float* __restrict__ bf,
    const float* __restrict__ Ws, const float* __restrict__ bs,
    float* __restrict__ coords4, float* __restrict__ feats)
{
    __shared__ __align__(16) float sW[FIN * WCOLS];
    __shared__ float sB[WCOLS];

    int t = threadIdx.x;
    for (int idx = t; idx < FIN * WCOLS; idx += 256) {
        int i = idx >> 5, c = idx & 31;
        float v = 0.f;
        if (c < PP) v = Wf[i * PP + c];
        else if (c >= 24 && c < 28) v = Ws[i * 4 + (c - 24)];
        sW[idx] = v;
    }
    if (t < WCOLS) {
        float v = 0.f;
        if (t < PP) v = bf[t];
        else if (t >= 24 && t < 28) v = bs[t - 24];
        sB[t] = v;
    }
    __syncthreads();

    int gid = blockIdx.x * 256 + t;
    int p = gid >> 2;          // point
    int h = gid & 3;           // column strip
    int c0 = h * 8;

    const float4* xr4 = (const float4*)(x + (size_t)p * FIN);
    float acc[8];
    #pragma unroll
    for (int k = 0; k < 8; ++k) acc[k] = sB[c0 + k];

    #pragma unroll
    for (int i = 0; i < 8; ++i) {
        float4 xt = xr4[i];
        const float* w0 = sW + (4 * i + 0) * WCOLS + c0;
        const float* w1 = sW + (4 * i + 1) * WCOLS + c0;
        const float* w2 = sW + (4 * i + 2) * WCOLS + c0;
        const float* w3 = sW + (4 * i + 3) * WCOLS + c0;
        #pragma unroll
        for (int k = 0; k < 8; ++k) acc[k] = fmaf(xt.x, w0[k], acc[k]);
        #pragma unroll
        for (int k = 0; k < 8; ++k) acc[k] = fmaf(xt.y, w1[k], acc[k]);
        #pragma unroll
        for (int k = 0; k < 8; ++k) acc[k] = fmaf(xt.z, w2[k], acc[k]);
        #pragma unroll
        for (int k = 0; k < 8; ++k) acc[k] = fmaf(xt.w, w3[k], acc[k]);
    }

    if (h < 3) {
        float4* fw = (float4*)(feats + (size_t)p * PPAD + c0);
        fw[0] = make_float4(acc[0], acc[1], acc[2], acc[3]);
        fw[1] = make_float4(acc[4], acc[5], acc[6], acc[7]);   // h=2: cols 22,23 exact 0
    } else {
        ((float4*)coords4)[p] = make_float4(acc[0], acc[1], acc[2], acc[3]);
    }
}

// ---- fallback-only helpers (degenerate C > CAP path) ----------------------------
__device__ __forceinline__ void sort64_pair(float& v, int& m, int lane) {
    #pragma unroll
    for (int k = 2; k <= 64; k <<= 1) {
        #pragma unroll
        for (int j = k >> 1; j >= 1; j >>= 1) {
            float ov = __shfl_xor(v, j);
            int   om = __shfl_xor(m, j);
            bool keepMin = (((lane & j) == 0) == ((lane & k) == 0));
            bool less = (ov < v) || (ov == v && om < m);
            bool take = (less == keepMin);
            v = take ? ov : v;
            m = take ? om : m;
        }
    }
}
__device__ __forceinline__ void merge64(float& Lv, int& Lm, float cv, int cm, int lane) {
    float rv = __shfl_xor(cv, 63);
    int   rm = __shfl_xor(cm, 63);
    bool less = (rv < Lv) || (rv == Lv && rm < Lm);
    if (less) { Lv = rv; Lm = rm; }
    #pragma unroll
    for (int j = 32; j >= 1; j >>= 1) {
        float ov = __shfl_xor(Lv, j);
        int   om = __shfl_xor(Lm, j);
        bool lower = ((lane & j) == 0);
        bool l2 = (ov < Lv) || (ov == Lv && om < Lm);
        bool take = (l2 == lower);
        Lv = take ? ov : Lv;
        Lm = take ? om : Lm;
    }
}

// ------- per-query selection + staging + packed aggregate (NO epilogue here) -----
// Selection math bit-identical to the verified kernel; s2 recomputed (same bits).
// Returns packed agg: lane c<22 -> max_c ; lane 22+c -> mean_c ; others 0.
__device__ __forceinline__ float tail_select(
    int lane, int b, int nj, int C,
    const unsigned short* __restrict__ selq,
    const float4* __restrict__ c4,
    const float* __restrict__ feats,
    float* __restrict__ fstage)
{
    const float INF = __builtin_inff();
    float4 cqj = c4[nj];
    float sqnj = sq4(cqj);

    if (C <= CAP) {
        unsigned kd0 = 0xFFFFFFFFu, ki0 = 0xFFFFFFFFu; float dv0 = 0.f;
        if (lane < C) {
            unsigned idx = (unsigned)selq[lane];
            float4 cm = c4[idx];
            float s2 = sq4(cm);
            float dt = fmaf(cqj.x, cm.x, fmaf(cqj.y, cm.y, fmaf(cqj.z, cm.z, cqj.w * cm.w)));
            float d  = fmaxf(fmaf(-2.f, dt, s2 + sqnj), 0.f);
            dv0 = d; kd0 = __float_as_uint(d); ki0 = idx;
        }
        unsigned kd1 = 0xFFFFFFFFu, ki1 = 0xFFFFFFFFu; float dv1 = 0.f;
        if (64 + lane < C) {
            unsigned idx = (unsigned)selq[64 + lane];
            float4 cm = c4[idx];
            float s2 = sq4(cm);
            float dt = fmaf(cqj.x, cm.x, fmaf(cqj.y, cm.y, fmaf(cqj.z, cm.z, cqj.w * cm.w)));
            float d  = fmaxf(fmaf(-2.f, dt, s2 + sqnj), 0.f);
            dv1 = d; kd1 = __float_as_uint(d); ki1 = idx;
        }
        // D = exact 39th-smallest clamped d2 bits (must stay exact)
        unsigned D = 0;
        for (int bit = 30; bit >= 0; --bit) {
            unsigned t = D | (1u << bit);
            int c = (int)__popcll(__ballot(kd0 < t))
                  + (int)__popcll(__ballot(kd1 < t));
            if (c < KSEL) D = t;
        }
        int cless  = (int)__popcll(__ballot(kd0 < D))
                   + (int)__popcll(__ballot(kd1 < D));
        int tiecnt = (int)__popcll(__ballot(kd0 == D))
                   + (int)__popcll(__ballot(kd1 == D));
        int tneed = KSEL - cless;
        unsigned TI = 0xFFFFFFFFu;
        if (tiecnt > tneed) {            // rare: resolve ties by lowest index
            unsigned pi = 0;
            for (int bit = 11; bit >= 0; --bit) {
                unsigned t = pi | (1u << bit);
                int c = (int)__popcll(__ballot((kd0 == D) && (ki0 < t)))
                      + (int)__popcll(__ballot((kd1 == D) && (ki1 < t)));
                if (c < tneed) pi = t;
            }
            TI = pi;
        }
        // stage the exactly-39 selected neighbors (ballot/prefix slots, no atomics)
        bool take0 = (kd0 < D) || ((kd0 == D) && (ki0 <= TI));
        bool take1 = (kd1 < D) || ((kd1 == D) && (ki1 <= TI));
        unsigned long long tb0 = __ballot(take0);
        unsigned long long tb1 = __ballot(take1);
        unsigned base1 = (unsigned)__popcll(tb0);
        if (take0) {
            unsigned slot = (unsigned)lane_prefix(tb0);
            float wgt = __expf(-10.f * dv0);
            const float4* fr = (const float4*)(feats + ((size_t)b * NN + ki0) * PPAD);
            float4 f0 = fr[0], f1 = fr[1], f2 = fr[2], f3 = fr[3], f4 = fr[4], f5 = fr[5];
            float4* row = (float4*)(fstage + slot * PPAD);
            row[0] = make_float4(f0.x * wgt, f0.y * wgt, f0.z * wgt, f0.w * wgt);
            row[1] = make_float4(f1.x * wgt, f1.y * wgt, f1.z * wgt, f1.w * wgt);
            row[2] = make_float4(f2.x * wgt, f2.y * wgt, f2.z * wgt, f2.w * wgt);
            row[3] = make_float4(f3.x * wgt, f3.y * wgt, f3.z * wgt, f3.w * wgt);
            row[4] = make_float4(f4.x * wgt, f4.y * wgt, f4.z * wgt, f4.w * wgt);
            row[5] = make_float4(f5.x * wgt, f5.y * wgt, f5.z * wgt, f5.w * wgt);
        }
        if (take1) {
            unsigned slot = base1 + (unsigned)lane_prefix(tb1);
            float wgt = __expf(-10.f * dv1);
            const float4* fr = (const float4*)(feats + ((size_t)b * NN + ki1) * PPAD);
            float4 f0 = fr[0], f1 = fr[1], f2 = fr[2], f3 = fr[3], f4 = fr[4], f5 = fr[5];
            float4* row = (float4*)(fstage + slot * PPAD);
            row[0] = make_float4(f0.x * wgt, f0.y * wgt, f0.z * wgt, f0.w * wgt);
            row[1] = make_float4(f1.x * wgt, f1.y * wgt, f1.z * wgt, f1.w * wgt);
            row[2] = make_float4(f2.x * wgt, f2.y * wgt, f2.z * wgt, f2.w * wgt);
            row[3] = make_float4(f3.x * wgt, f3.y * wgt, f3.z * wgt, f3.w * wgt);
            row[4] = make_float4(f4.x * wgt, f4.y * wgt, f4.z * wgt, f4.w * wgt);
            row[5] = make_float4(f5.x * wgt, f5.y * wgt, f5.z * wgt, f5.w * wgt);
        }
    } else {
        // degenerate fallback: exact streaming top-64 over all 4096
        float Lv = INF; int Lm = 0x7FFFFFFF;
        for (int c = 0; c < 64; ++c) {
            int m = c * 64 + lane;
            float4 cm = c4[m];
            float s2 = sq4(cm);
            float dt = fmaf(cqj.x, cm.x, fmaf(cqj.y, cm.y, fmaf(cqj.z, cm.z, cqj.w * cm.w)));
            float v  = fmaxf(fmaf(-2.f, dt, s2 + sqnj), 0.f);
            if (m == nj) v = INF;
            sort64_pair(v, m, lane);
            if (c == 0) { Lv = v; Lm = m; }
            else        merge64(Lv, Lm, v, m, lane);
        }
        if (lane < KSEL) {
            float wgt = __expf(-10.f * Lv);
            const float4* fr = (const float4*)(feats + ((size_t)b * NN + Lm) * PPAD);
            float4 f0 = fr[0], f1 = fr[1], f2 = fr[2], f3 = fr[3], f4 = fr[4], f5 = fr[5];
            float4* row = (float4*)(fstage + lane * PPAD);
            row[0] = make_float4(f0.x * wgt, f0.y * wgt, f0.z * wgt, f0.w * wgt);
            row[1] = make_float4(f1.x * wgt, f1.y * wgt, f1.z * wgt, f1.w * wgt);
            row[2] = make_float4(f2.x * wgt, f2.y * wgt, f2.z * wgt, f2.w * wgt);
            row[3] = make_float4(f3.x * wgt, f3.y * wgt, f3.z * wgt, f3.w * wgt);
            row[4] = make_float4(f4.x * wgt, f4.y * wgt, f4.z * wgt, f4.w * wgt);
            row[5] = make_float4(f5.x * wgt, f5.y * wgt, f5.z * wgt, f5.w * wgt);
        }
    }
    WSYNC();

    // ---- packed aggregate over 39 neighbors: lanes 0..43 (round-6 form) ----
    float aggv = 0.f;
    if (lane < 2 * PP) {
        int c = (lane < PP) ? lane : lane - PP;
        float mx = -INF, sm = 0.f;
        for (int k = 0; k < KSEL; ++k) {
            float v = fstage[k * PPAD + c];
            mx = fmaxf(mx, v);
            sm += v;
        }
        aggv = (lane < PP) ? mx : sm * (1.f / (float)KSEL);
    }
    WSYNC();
    return aggv;
}

// ---------------- main: one wave per FOUR queries, fused epilogue ----------------
__global__ __launch_bounds__(WPB * 64, 8) void gn_main(
    const float* __restrict__ x,
    const float* __restrict__ Wo, const float* __restrict__ bo,
    const float* __restrict__ coords4,
    const float* __restrict__ feats,
    float* __restrict__ out)
{
    __shared__ unsigned short sel_s[WPB * QW * CAP];     // candidate indices
    __shared__ float fstage_s[WPB * KSEL * PPAD];
    __shared__ unsigned cnt_s[WPB * QW];                 // compact slot counters

    const float INF = __builtin_inff();
    const int wv    = threadIdx.x >> 6;
    const int lane  = threadIdx.x & 63;
    const int qbase = (blockIdx.x * WPB + wv) * QW;      // 4 queries, same batch
    const int b     = qbase >> 12;
    const int n0    = qbase & (NN - 1);
    unsigned short* selp = sel_s + wv * QW * CAP;
    unsigned* cnt = cnt_s + wv * QW;
    float* fstage = fstage_s + wv * (KSEL * PPAD);

    const float4* c4 = ((const float4*)coords4) + (size_t)b * NN;

    if (lane < QW) cnt[lane] = 0;

    // hoisted -2*q components (query coords NOT kept live -- tails reload them).
    // e = s2 - 2*dot with s2 recomputed (bit-identical chain). Selection in
    // e-domain; widened bound keeps an exact superset; tails re-rank exactly.
    float4 cq0 = c4[n0 + 0], cq1 = c4[n0 + 1], cq2 = c4[n0 + 2], cq3 = c4[n0 + 3];
    float m2x0 = -2.f * cq0.x, m2y0 = -2.f * cq0.y, m2z0 = -2.f * cq0.z, m2w0 = -2.f * cq0.w;
    float m2x1 = -2.f * cq1.x, m2y1 = -2.f * cq1.y, m2z1 = -2.f * cq1.z, m2w1 = -2.f * cq1.w;
    float m2x2 = -2.f * cq2.x, m2y2 = -2.f * cq2.y, m2z2 = -2.f * cq2.z, m2w2 = -2.f * cq2.w;
    float m2x3 = -2.f * cq3.x, m2y3 = -2.f * cq3.y, m2z3 = -2.f * cq3.z, m2w3 = -2.f * cq3.w;

    // ---- pass 1: per-query running min of e (self included) ----
    float km0 = INF, km1 = INF, km2 = INF, km3 = INF;
    #pragma unroll 4
    for (int i = 0; i < 64; ++i) {
        float4 cm = c4[i * 64 + lane];
        float s2  = sq4(cm);
        float e0 = fmaf(m2x0, cm.x, fmaf(m2y0, cm.y, fmaf(m2z0, cm.z, fmaf(m2w0, cm.w, s2))));
        float e1 = fmaf(m2x1, cm.x, fmaf(m2y1, cm.y, fmaf(m2z1, cm.z, fmaf(m2w1, cm.w, s2))));
        float e2 = fmaf(m2x2, cm.x, fmaf(m2y2, cm.y, fmaf(m2z2, cm.z, fmaf(m2w2, cm.w, s2))));
        float e3 = fmaf(m2x3, cm.x, fmaf(m2y3, cm.y, fmaf(m2z3, cm.z, fmaf(m2w3, cm.w, s2))));
        km0 = fminf(km0, e0);
        km1 = fminf(km1, e1);
        km2 = fminf(km2, e2);
        km3 = fminf(km3, e3);
    }
    unsigned kb0 = ford(km0), kb1 = ford(km1), kb2 = ford(km2), kb3 = ford(km3);

    // ---- bound: 40th-smallest lane-min key, TRUNCATED radix (bits 31..15),
    //      widen low 15 bits -> guaranteed >= exact 40th e. Exact superset.
    unsigned ub0 = 0, ub1 = 0, ub2 = 0, ub3 = 0;
    for (int bit = 31; bit >= 15; --bit) {
        unsigned msk = 1u << bit;
        unsigned t0 = ub0 | msk, t1 = ub1 | msk, t2 = ub2 | msk, t3 = ub3 | msk;
        if ((int)__popcll(__ballot(kb0 < t0)) < KSEL + 1) ub0 = t0;
        if ((int)__popcll(__ballot(kb1 < t1)) < KSEL + 1) ub1 = t1;
        if ((int)__popcll(__ballot(kb2 < t2)) < KSEL + 1) ub2 = t2;
        if ((int)__popcll(__ballot(kb3 < t3)) < KSEL + 1) ub3 = t3;
    }
    float UBe0 = funord(ub0 | 0x7FFFu);
    float UBe1 = funord(ub1 | 0x7FFFu);
    float UBe2 = funord(ub2 | 0x7FFFu);
    float UBe3 = funord(ub3 | 0x7FFFu);

    // selves all sit in iteration iSelf at lanes l0..l0+3 (n0 % 4 == 0)
    const int iSelf = n0 >> 6;
    const int l0    = n0 & 63;
    WSYNC();                                   // cnt init visible (wave-local)

    // ---- compact pass: LDS atomic slot assignment (VALU -> LDS-pipe trade) ----
    #pragma unroll 4
    for (int i = 0; i < 64; ++i) {
        int m = i * 64 + lane;
        float4 cm = c4[m];
        float s2  = sq4(cm);
        float e0 = fmaf(m2x0, cm.x, fmaf(m2y0, cm.y, fmaf(m2z0, cm.z, fmaf(m2w0, cm.w, s2))));
        float e1 = fmaf(m2x1, cm.x, fmaf(m2y1, cm.y, fmaf(m2z1, cm.z, fmaf(m2w1, cm.w, s2))));
        float e2 = fmaf(m2x2, cm.x, fmaf(m2y2, cm.y, fmaf(m2z2, cm.z, fmaf(m2w2, cm.w, s2))));
        float e3 = fmaf(m2x3, cm.x, fmaf(m2y3, cm.y, fmaf(m2z3, cm.z, fmaf(m2w3, cm.w, s2))));
        bool t0 = (e0 <= UBe0);
        bool t1 = (e1 <= UBe1);
        bool t2 = (e2 <= UBe2);
        bool t3 = (e3 <= UBe3);
        if (i == iSelf) {                      // wave-uniform, 1 of 64 iters
            t0 = t0 && (lane != l0 + 0);
            t1 = t1 && (lane != l0 + 1);
            t2 = t2 && (lane != l0 + 2);
            t3 = t3 && (lane != l0 + 3);
        }
        if (t0) {
            unsigned s = atomicAdd(&cnt[0], 1u) & (CAP - 1);
            selp[0 * CAP + s] = (unsigned short)m;
        }
        if (t1) {
            unsigned s = atomicAdd(&cnt[1], 1u) & (CAP - 1);
            selp[1 * CAP + s] = (unsigned short)m;
        }
        if (t2) {
            unsigned s = atomicAdd(&cnt[2], 1u) & (CAP - 1);
            selp[2 * CAP + s] = (unsigned short)m;
        }
        if (t3) {
            unsigned s = atomicAdd(&cnt[3], 1u) & (CAP - 1);
            selp[3 * CAP + s] = (unsigned short)m;
        }
    }
    WSYNC();
    int cc0 = (int)cnt[0];
    int cc1 = (int)cnt[1];
    int cc2 = (int)cnt[2];
    int cc3 = (int)cnt[3];
    WSYNC();

    // ---- four selection/aggregate tails (packed agg kept in VGPRs) ----
    float agg0 = tail_select(lane, b, n0 + 0, cc0, selp + 0 * CAP, c4, feats, fstage);
    float agg1 = tail_select(lane, b, n0 + 1, cc1, selp + 1 * CAP, c4, feats, fstage);
    float agg2 = tail_select(lane, b, n0 + 2, cc2, selp + 2 * CAP, c4, feats, fstage);
    float agg3 = tail_select(lane, b, n0 + 3, cc3, selp + 3 * CAP, c4, feats, fstage);

    // ---- FUSED epilogue: Wo loaded ONCE for all 4 queries; x via scalar loads ----
    const int qbU = __builtin_amdgcn_readfirstlane(qbase);
    const float* xu = x + (size_t)qbU * FIN;             // uniform -> SMEM loads
    if (lane < FOUT) {
        const float* woL = Wo + lane;
        float bb = bo[lane];
        float a00 = bb, a01 = 0.f, a02 = 0.f, a03 = 0.f;
        float a10 = bb, a11 = 0.f, a12 = 0.f, a13 = 0.f;
        float a20 = bb, a21 = 0.f, a22 = 0.f, a23 = 0.f;
        float a30 = bb, a31 = 0.f, a32 = 0.f, a33 = 0.f;
        #pragma unroll
        for (int f = 0; f < FIN; f += 4) {
            float w0 = woL[(f + 0) * FOUT];
            float w1 = woL[(f + 1) * FOUT];
            float w2 = woL[(f + 2) * FOUT];
            float w3 = woL[(f + 3) * FOUT];
            a00 = fmaf(xu[0 * FIN + f + 0], w0, a00);
            a01 = fmaf(xu[0 * FIN + f + 1], w1, a01);
            a02 = fmaf(xu[0 * FIN + f + 2], w2, a02);
            a03 = fmaf(xu[0 * FIN + f + 3], w3, a03);
            a10 = fmaf(xu[1 * FIN + f + 0], w0, a10);
            a11 = fmaf(xu[1 * FIN + f + 1], w1, a11);
            a12 = fmaf(xu[1 * FIN + f + 2], w2, a12);
            a13 = fmaf(xu[1 * FIN + f + 3], w3, a13);
            a20 = fmaf(xu[2 * FIN + f + 0], w0, a20);
            a21 = fmaf(xu[2 * FIN + f + 1], w1, a21);
            a22 = fmaf(xu[2 * FIN + f + 2], w2, a22);
            a23 = fmaf(xu[2 * FIN + f + 3], w3, a23);
            a30 = fmaf(xu[3 * FIN + f + 0], w0, a30);
            a31 = fmaf(xu[3 * FIN + f + 1], w1, a31);
            a32 = fmaf(xu[3 * FIN + f + 2], w2, a32);
            a33 = fmaf(xu[3 * FIN + f + 3], w3, a33);
        }
        #pragma unroll
        for (int g = 0; g < 2 * PP; g += 4) {
            float w0 = woL[(FIN + g + 0) * FOUT];
            float w1 = woL[(FIN + g + 1) * FOUT];
            float w2 = woL[(FIN + g + 2) * FOUT];
            float w3 = woL[(FIN + g + 3) * FOUT];
            a00 = fmaf(lane_bcast(agg0, g + 0), w0, a00);
            a01 = fmaf(lane_bcast(agg0, g + 1), w1, a01);
            a02 = fmaf(lane_bcast(agg0, g + 2), w2, a02);
            a03 = fmaf(lane_bcast(agg0, g + 3), w3, a03);
            a10 = fmaf(lane_bcast(agg1, g + 0), w0, a10);
            a11 = fmaf(lane_bcast(agg1, g + 1), w1, a11);
            a12 = fmaf(lane_bcast(agg1, g + 2), w2, a12);
            a13 = fmaf(lane_bcast(agg1, g + 3), w3, a13);
            a20 = fmaf(lane_bcast(agg2, g + 0), w0, a20);
            a21 = fmaf(lane_bcast(agg2, g + 1), w1, a21);
            a22 = fmaf(lane_bcast(agg2, g + 2), w2, a22);
            a23 = fmaf(lane_bcast(agg2, g + 3), w3, a23);
            a30 = fmaf(lane_bcast(agg3, g + 0), w0, a30);
            a31 = fmaf(lane_bcast(agg3, g + 1), w1, a31);
            a32 = fmaf(lane_bcast(agg3, g + 2), w2, a32);
            a33 = fmaf(lane_bcast(agg3, g + 3), w3, a33);
        }
        float ac0 = (a00 + a01) + (a02 + a03);
        float ac1 = (a10 + a11) + (a12 + a13);
        float ac2 = (a20 + a21) + (a22 + a23);
        float ac3 = (a30 + a31) + (a32 + a33);
        float e0 = __expf(2.f * ac0);
        float e1 = __expf(2.f * ac1);
        float e2 = __expf(2.f * ac2);
        float e3 = __expf(2.f * ac3);
        float r0 = __builtin_amdgcn_rcpf(e0 + 1.f);
        float r1 = __builtin_amdgcn_rcpf(e1 + 1.f);
        float r2 = __builtin_amdgcn_rcpf(e2 + 1.f);
        float r3 = __builtin_amdgcn_rcpf(e3 + 1.f);
        out[(size_t)(qbU + 0) * FOUT + lane] = fmaf(-2.f, r0, 1.f);
        out[(size_t)(qbU + 1) * FOUT + lane] = fmaf(-2.f, r1, 1.f);
        out[(size_t)(qbU + 2) * FOUT + lane] = fmaf(-2.f, r2, 1.f);
        out[(size_t)(qbU + 3) * FOUT + lane] = fmaf(-2.f, r3, 1.f);
    }
}

extern "C" void kernel_launch(void* const* d_in, const int* in_sizes, int n_in,
                              void* d_out, int out_size, void* d_ws, size_t ws_size,
                              hipStream_t stream) {
    const float* x  = (const float*)d_in[0];
    const float* Wf = (const float*)d_in[1];
    const float* bf = (const float*)d_in[2];
    const float* Ws = (const float*)d_in[3];
    const float* bs = (const float*)d_in[4];
    const float* Wo = (const float*)d_in[5];
    const float* bo = (const float*)d_in[6];
    float* outp = (float*)d_out;

    float* ws      = (float*)d_ws;
    float* coords4 = ws;                      // 32768*4  = 131072 floats
    float* feats   = ws + 131072;             // 32768*24 = 786432 floats

    gn_pre<<<(32768 * 4) / 256, 256, 0, stream>>>(x, Wf, bf, Ws, bs, coords4, feats);
    gn_main<<<32768 / (WPB * QW), WPB * 64, 0, stream>>>(x, Wo, bo, coords4, feats, outp);
}